// Round 4
// baseline (371.140 us; speedup 1.0000x reference)
//
#include <hip/hip_runtime.h>

// MPRelativeSelfMultiheadAttn on gfx950.
// streaming hypernet (8 rows/thread, 16 loads in flight) -> fp16 MFMA GEMMs
// (global_load_lds with XOR-swizzled gather => conflict-free ds_read_b128,
// V written transposed in epilogue) -> j-split(4) flash attention (rel_shift
// fused, online softmax) -> combine -> out GEMM.
// XOR swizzle: LDS(row, g) = global(row, g ^ (row&7)), granule = 16B.

typedef _Float16 h16;
typedef _Float16 h16x8 __attribute__((ext_vector_type(8)));
typedef _Float16 h16x4 __attribute__((ext_vector_type(4)));
typedef float f32x4 __attribute__((ext_vector_type(4)));

static __device__ __forceinline__ f32x4 mfma16(h16x8 a, h16x8 b, f32x4 c) {
  return __builtin_amdgcn_mfma_f32_16x16x32_f16(a, b, c, 0, 0, 0);
}
static __device__ __forceinline__ void gload16(const void* g, void* l) {
  __builtin_amdgcn_global_load_lds((const __attribute__((address_space(1))) void*)g,
                                   (__attribute__((address_space(3))) void*)l, 16, 0, 0);
}

// ---------------- hypernet + casts, streaming ----------------
// blocks [0,2560): 5.24M weight rows, 8/thread. [2560,2596): biases+rb pad.
// [2596,3364): fp32->fp16 casts, 8 float4/thread.
__global__ __launch_bounds__(256) void hypernet_kernel(
    const float* __restrict__ fac,
    const float* __restrict__ w_in, const float* __restrict__ w_pos,
    const float* __restrict__ w_out, const float* __restrict__ b_in_w,
    const float* __restrict__ b_pos_w, const float* __restrict__ b_out_w,
    const float* __restrict__ rw_w, const float* __restrict__ rr_w,
    h16* __restrict__ Wall,                 // Win|Wpos|Wout contiguous
    float* __restrict__ bin, float* __restrict__ bpos, float* __restrict__ bout,
    float* __restrict__ rw, float* __restrict__ rr, h16* __restrict__ rb,
    const float* __restrict__ input, const float* __restrict__ pos,
    h16* __restrict__ cast_h)               // in_h|pos_h contiguous
{
  const int tid = threadIdx.x;
  const float f0=fac[0],f1=fac[1],f2=fac[2],f3=fac[3],
              f4=fac[4],f5=fac[5],f6=fac[6],f7=fac[7];
#define DOT(a,b) ((a).x*f0+(a).y*f1+(a).z*f2+(a).w*f3+(b).x*f4+(b).y*f5+(b).z*f6+(b).w*f7)

  if (blockIdx.x < 2560) {                  // weight rows
    const int base = blockIdx.x * 2048 + tid;
    float4 va[8], vb[8];
#pragma unroll
    for (int k = 0; k < 8; ++k) {
      int r = base + k*256;
      const float4* s;
      if (r < 3145728)      s = reinterpret_cast<const float4*>(w_in  + (size_t)r*8);
      else if (r < 4194304) s = reinterpret_cast<const float4*>(w_pos + (size_t)(r-3145728)*8);
      else                  s = reinterpret_cast<const float4*>(w_out + (size_t)(r-4194304)*8);
      va[k] = s[0]; vb[k] = s[1];
    }
#pragma unroll
    for (int k = 0; k < 8; ++k)
      Wall[base + k*256] = (h16)DOT(va[k], vb[k]);
    return;
  }
  if (blockIdx.x < 2596) {                  // biases + rb pad
    int idx = (blockIdx.x - 2560) * 256 + tid;
    if (idx < 3072) {
      const float4* s = reinterpret_cast<const float4*>(b_in_w + (size_t)idx*8);
      bin[idx] = DOT(s[0], s[1]); return;
    }
    idx -= 3072;
    if (idx < 1024) {
      const float4* s = reinterpret_cast<const float4*>(b_pos_w + (size_t)idx*8);
      bpos[idx] = DOT(s[0], s[1]); return;
    }
    idx -= 1024;
    if (idx < 1024) {
      const float4* s = reinterpret_cast<const float4*>(b_out_w + (size_t)idx*8);
      bout[idx] = DOT(s[0], s[1]); return;
    }
    idx -= 1024;
    if (idx < 1024) {
      const float4* s = reinterpret_cast<const float4*>(rw_w + (size_t)idx*8);
      rw[idx] = DOT(s[0], s[1]); return;
    }
    idx -= 1024;
    if (idx < 1024) {
      const float4* s = reinterpret_cast<const float4*>(rr_w + (size_t)idx*8);
      rr[idx] = DOT(s[0], s[1]); return;
    }
    idx -= 1024;
    if (idx < 2048)
      rb[(((size_t)(idx >> 6)) << 17) + 2047*64 + (idx & 63)] = (h16)0.f;
    return;
  }
  { // casts: float4 index space [0, 1572352) = input(524288) | pos(1048064)
    const int base = (blockIdx.x - 2596) * 2048 + tid;
    float4 v[8]; int g[8];
#pragma unroll
    for (int k = 0; k < 8; ++k) {
      g[k] = base + k*256;
      if (g[k] < 1572352)
        v[k] = (g[k] < 524288) ? reinterpret_cast<const float4*>(input)[g[k]]
                               : reinterpret_cast<const float4*>(pos)[g[k] - 524288];
    }
#pragma unroll
    for (int k = 0; k < 8; ++k)
      if (g[k] < 1572352) {
        h16x4 o = { (h16)v[k].x, (h16)v[k].y, (h16)v[k].z, (h16)v[k].w };
        reinterpret_cast<h16x4*>(cast_h)[g[k]] = o;
      }
  }
#undef DOT
}

// ---------------- GEMM C = A[MxK] * Bw[NxK]^T, swizzled global_load_lds ----------------
// MODE 0: qkv -> qrw,qrr,kb per-head + V transposed into vbt
// MODE 1: r -> rb; MODE 2: fp32 C + bias
template <int MODE>
__global__ __launch_bounds__(256) void gemm_lds_kernel(
    const h16* __restrict__ A, const h16* __restrict__ Bw,
    const float* __restrict__ bias, int M, int N, int K,
    float* __restrict__ Cout,
    const float* __restrict__ rwv, const float* __restrict__ rrv,
    h16* __restrict__ o0, h16* __restrict__ o1,
    h16* __restrict__ o2, h16* __restrict__ o3)
{
  __shared__ __align__(16) h16 a_sm[128*64];
  __shared__ __align__(16) h16 b_sm[128*64];
  const int tid = threadIdx.x, lane = tid & 63, wave = tid >> 6;
  const int quad = lane >> 4, t16 = lane & 15;
  const int wm = wave >> 1, wn = wave & 1;
  const int m0 = blockIdx.y * 128, n0 = blockIdx.x * 128;
  const int lrow = lane >> 3, lgran = lane & 7;
  const int gsw = (lgran ^ lrow) * 8;          // swizzled source col offset (h16)
  const int xg0 = (quad ^ (t16 & 7)) * 8;      // fragment granule, kc=0
  const int xg1 = xg0 ^ 32;                    // kc=1

  f32x4 acc[4][4];
#pragma unroll
  for (int i = 0; i < 4; ++i)
#pragma unroll
    for (int j = 0; j < 4; ++j) acc[i][j] = (f32x4){0.f,0.f,0.f,0.f};

  for (int k0 = 0; k0 < K; k0 += 64) {
    __syncthreads();
#pragma unroll
    for (int s = 0; s < 4; ++s) {
      int rbase = wave*32 + s*8;
      gload16(A  + (size_t)(m0 + rbase + lrow)*K + k0 + gsw, a_sm + rbase*64);
      gload16(Bw + (size_t)(n0 + rbase + lrow)*K + k0 + gsw, b_sm + rbase*64);
    }
    __syncthreads();
#pragma unroll
    for (int kc = 0; kc < 2; ++kc) {
      const int xg = kc ? xg1 : xg0;
      h16x8 af[4], bfr[4];
#pragma unroll
      for (int i = 0; i < 4; ++i) {
        af[i]  = *reinterpret_cast<const h16x8*>(a_sm + (wm*64 + i*16 + t16)*64 + xg);
        bfr[i] = *reinterpret_cast<const h16x8*>(b_sm + (wn*64 + i*16 + t16)*64 + xg);
      }
#pragma unroll
      for (int i = 0; i < 4; ++i)
#pragma unroll
        for (int j = 0; j < 4; ++j)
          acc[i][j] = mfma16(af[i], bfr[j], acc[i][j]);
    }
  }

  // epilogue: C/D layout row=(lane>>4)*4+reg, col=lane&15
#pragma unroll
  for (int i = 0; i < 4; ++i) {
    int mb = m0 + wm*64 + i*16 + quad*4;
#pragma unroll
    for (int j = 0; j < 4; ++j) {
      int n = n0 + wn*64 + j*16 + t16;
      float bv = bias[n];
      if (MODE == 2) {
#pragma unroll
        for (int r = 0; r < 4; ++r)
          Cout[(size_t)(mb + r)*N + n] = acc[i][j][r] + bv;
      } else if (MODE == 0) {
        int nn = n & 1023, sec = n >> 10, hh = nn >> 6, d = nn & 63;
        float rwb = rwv[nn], rrb = rrv[nn];
#pragma unroll
        for (int r = 0; r < 4; ++r) {
          int m = mb + r, t = m >> 1, b = m & 1;
          size_t hbase = (size_t)((b << 4) + hh) << 16;
          float v = acc[i][j][r] + bv;
          if (sec == 0)      { o0[hbase + (t << 6) + d] = (h16)(v + rwb);
                               o1[hbase + (t << 6) + d] = (h16)(v + rrb); }
          else if (sec == 1) { o2[hbase + (t << 6) + d] = (h16)v; }
          else               { o3[hbase + (d << 10) + t] = (h16)v; }   // V transposed
        }
      } else { // MODE 1
        int hh = n >> 6, d = n & 63;
#pragma unroll
        for (int r = 0; r < 4; ++r) {
          int m = mb + r;
          if (m < M) {
            int rel = m >> 1, b = m & 1;
            o0[(((size_t)((b << 4) + hh)) << 17) + (rel << 6) + d] = (h16)(acc[i][j][r] + bv);
          }
        }
      }
    }
  }
}

// ---------------- flash attention, j-split(4), swizzled staging ----------------
__global__ __launch_bounds__(256) void flash_kernel(
    const h16* __restrict__ qrw, const h16* __restrict__ qrr,
    const h16* __restrict__ kb, const h16* __restrict__ vbt,
    const h16* __restrict__ rb,
    float* __restrict__ o_part, float* __restrict__ ml_part)
{
  __shared__ __align__(16) h16 k_sm[64*64];
  __shared__ __align__(16) h16 vt_sm[64*64];
  __shared__ __align__(16) h16 r_sm[128*64];   // reused as BD/P spill after barrier

  const int tid = threadIdx.x, lane = tid & 63, wave = tid >> 6;
  const int quad = lane >> 4, t16 = lane & 15;
  const int bh = blockIdx.y, i0 = blockIdx.x * 64, jh = blockIdx.z;
  const size_t base  = (size_t)bh << 16;
  const size_t rbase = (size_t)bh << 17;
  const int iw = i0 + wave * 16;
  const int lrow = lane >> 3, lgran = lane & 7;
  const int gsw = (lgran ^ lrow) * 8;
  const int xg0 = (quad ^ (t16 & 7)) * 8;
  const int xg1 = xg0 ^ 32;

  h16x8 a_rw[2], a_rr[2];
  {
    const h16* p = qrw + base + (size_t)(iw + t16)*64 + quad*8;
    a_rw[0] = *reinterpret_cast<const h16x8*>(p);
    a_rw[1] = *reinterpret_cast<const h16x8*>(p + 32);
    const h16* p2 = qrr + base + (size_t)(iw + t16)*64 + quad*8;
    a_rr[0] = *reinterpret_cast<const h16x8*>(p2);
    a_rr[1] = *reinterpret_cast<const h16x8*>(p2 + 32);
  }

  f32x4 o_acc[4];
#pragma unroll
  for (int dc = 0; dc < 4; ++dc) o_acc[dc] = (f32x4){0.f,0.f,0.f,0.f};
  float m_run[4] = {-1e30f,-1e30f,-1e30f,-1e30f};
  float l_run[4] = {0.f,0.f,0.f,0.f};   // per-lane partial; reduced at end

  h16* bdw = r_sm + wave * (16*84);
  const int cb0 = 3 - wave;

  for (int j0 = jh*256; j0 < jh*256 + 256; j0 += 64) {
    __syncthreads();
    { // swizzled staging
#pragma unroll
      for (int s = 0; s < 2; ++s) {
        int row = wave*16 + s*8;
        gload16(kb  + base + (size_t)(j0 + row + lrow)*64 + gsw, k_sm  + row*64);
        gload16(vbt + base + (size_t)(row + lrow)*1024 + j0 + gsw, vt_sm + row*64);
      }
      const int rel0 = j0 - i0 + 960;
#pragma unroll
      for (int s = 0; s < 4; ++s) {
        int row = wave*32 + s*8;
        gload16(rb + rbase + (size_t)(rel0 + row + lrow)*64 + gsw, r_sm + row*64);
      }
    }
    __syncthreads();

    f32x4 s_ac[4];
#pragma unroll
    for (int c = 0; c < 4; ++c) {
      s_ac[c] = (f32x4){0.f,0.f,0.f,0.f};
      s_ac[c] = mfma16(a_rw[0], *reinterpret_cast<const h16x8*>(k_sm + (c*16 + t16)*64 + xg0), s_ac[c]);
      s_ac[c] = mfma16(a_rw[1], *reinterpret_cast<const h16x8*>(k_sm + (c*16 + t16)*64 + xg1), s_ac[c]);
    }
    f32x4 s_bd[5];
#pragma unroll
    for (int u = 0; u < 5; ++u) {
      s_bd[u] = (f32x4){0.f,0.f,0.f,0.f};
      s_bd[u] = mfma16(a_rr[0], *reinterpret_cast<const h16x8*>(r_sm + ((cb0+u)*16 + t16)*64 + xg0), s_bd[u]);
      s_bd[u] = mfma16(a_rr[1], *reinterpret_cast<const h16x8*>(r_sm + ((cb0+u)*16 + t16)*64 + xg1), s_bd[u]);
    }
    __syncthreads();  // r_sm reads done before spilling into it

    // BD spill (C-layout), stride 84
#pragma unroll
    for (int u = 0; u < 5; ++u)
#pragma unroll
      for (int r = 0; r < 4; ++r)
        bdw[(quad*4 + r)*84 + u*16 + t16] = (h16)s_bd[u][r];

    // combine with relative shift
    float sv[4][4];
#pragma unroll
    for (int c = 0; c < 4; ++c)
#pragma unroll
      for (int r = 0; r < 4; ++r) {
        int il = quad*4 + r;
        float bdv = (float)bdw[il*84 + c*16 + t16 + 15 - il];
        sv[c][r] = (s_ac[c][r] + bdv) * 0.125f;
      }

    // online softmax: shared row max (shfl), per-lane l partial
    float alpha[4];
#pragma unroll
    for (int r = 0; r < 4; ++r) {
      float v = fmaxf(fmaxf(sv[0][r], sv[1][r]), fmaxf(sv[2][r], sv[3][r]));
#pragma unroll
      for (int off = 1; off < 16; off <<= 1) v = fmaxf(v, __shfl_xor(v, off, 64));
      float mn = fmaxf(m_run[r], v);
      alpha[r] = __expf(m_run[r] - mn);
      m_run[r] = mn;
    }
#pragma unroll
    for (int r = 0; r < 4; ++r) {
      float s0 = 0.f;
#pragma unroll
      for (int c = 0; c < 4; ++c) {
        float p = __expf(sv[c][r] - m_run[r]);
        sv[c][r] = p; s0 += p;
      }
      l_run[r] = l_run[r]*alpha[r] + s0;   // per-lane; reduce at end
    }
#pragma unroll
    for (int dc = 0; dc < 4; ++dc) {
      f32x4 t = o_acc[dc];
#pragma unroll
      for (int r = 0; r < 4; ++r) t[r] *= alpha[r];
      o_acc[dc] = t;
    }
    // P round-trip (stride 72, 2-way free)
    h16* pw = bdw;
#pragma unroll
    for (int c = 0; c < 4; ++c)
#pragma unroll
      for (int r = 0; r < 4; ++r)
        pw[(quad*4 + r)*72 + c*16 + t16] = (h16)sv[c][r];

    h16x8 ap0 = *reinterpret_cast<const h16x8*>(pw + t16*72 + quad*8);
    h16x8 ap1 = *reinterpret_cast<const h16x8*>(pw + t16*72 + 32 + quad*8);
#pragma unroll
    for (int dc = 0; dc < 4; ++dc) {
      h16x8 bv0 = *reinterpret_cast<const h16x8*>(vt_sm + (dc*16 + t16)*64 + xg0);
      h16x8 bv1 = *reinterpret_cast<const h16x8*>(vt_sm + (dc*16 + t16)*64 + xg1);
      o_acc[dc] = mfma16(ap0, bv0, o_acc[dc]);
      o_acc[dc] = mfma16(ap1, bv1, o_acc[dc]);
    }
  }

  // reduce l across the quad's 16 lanes, then write partials
#pragma unroll
  for (int r = 0; r < 4; ++r) {
    float l = l_run[r];
#pragma unroll
    for (int off = 1; off < 16; off <<= 1) l += __shfl_xor(l, off, 64);
    l_run[r] = l;
  }
  const size_t obase = ((size_t)jh*32 + bh) * 1024 * 64;
#pragma unroll
  for (int r = 0; r < 4; ++r) {
    int i = iw + quad*4 + r;
#pragma unroll
    for (int dc = 0; dc < 4; ++dc)
      o_part[obase + (size_t)i*64 + dc*16 + t16] = o_acc[dc][r];
    if (t16 == 0) {
      size_t mo = (((size_t)jh*32 + bh)*1024 + i)*2;
      ml_part[mo]     = m_run[r];
      ml_part[mo + 1] = l_run[r];
    }
  }
}

// ---------------- combine 4 j-parts -> attn_h [(t*2+b)][E] h16 ----------------
__global__ __launch_bounds__(256) void combine_kernel(
    const float* __restrict__ o_part, const float* __restrict__ ml_part,
    h16* __restrict__ attn_h)
{
  int gid = blockIdx.x * 256 + threadIdx.x;   // 524288
  int row = gid >> 4;                          // bh*1024 + i
  int d4 = (gid & 15) * 4;
  float m[4], l[4];
#pragma unroll
  for (int p = 0; p < 4; ++p) {
    m[p] = ml_part[p*65536 + row*2];
    l[p] = ml_part[p*65536 + row*2 + 1];
  }
  float M = fmaxf(fmaxf(m[0], m[1]), fmaxf(m[2], m[3]));
  float e[4], den = 0.f;
#pragma unroll
  for (int p = 0; p < 4; ++p) { e[p] = __expf(m[p] - M); den += e[p]*l[p]; }
  float inv = 1.f / den;
  float4 acc = {0.f,0.f,0.f,0.f};
#pragma unroll
  for (int p = 0; p < 4; ++p) {
    float4 O = *reinterpret_cast<const float4*>(o_part + (size_t)p*2097152 + (size_t)row*64 + d4);
    acc.x += e[p]*O.x; acc.y += e[p]*O.y; acc.z += e[p]*O.z; acc.w += e[p]*O.w;
  }
  int bh = row >> 10, i = row & 1023, b = bh >> 4, h = bh & 15;
  h16x4 o = { (h16)(acc.x*inv), (h16)(acc.y*inv), (h16)(acc.z*inv), (h16)(acc.w*inv) };
  *reinterpret_cast<h16x4*>(attn_h + ((size_t)(i*2 + b))*1024 + h*64 + d4) = o;
}

extern "C" void kernel_launch(void* const* d_in, const int* in_sizes, int n_in,
                              void* d_out, int out_size, void* d_ws, size_t ws_size,
                              hipStream_t stream)
{
  const float* input  = (const float*)d_in[0];
  const float* pos    = (const float*)d_in[1];
  const float* fac    = (const float*)d_in[2];
  const float* w_in   = (const float*)d_in[3];
  const float* w_pos  = (const float*)d_in[4];
  const float* w_out  = (const float*)d_in[5];
  const float* bin_w  = (const float*)d_in[6];
  const float* bpos_w = (const float*)d_in[7];
  const float* bout_w = (const float*)d_in[8];
  const float* rw_w   = (const float*)d_in[9];
  const float* rr_w   = (const float*)d_in[10];
  float* out = (float*)d_out;
  (void)in_sizes; (void)n_in; (void)out_size; (void)ws_size;

  char* w = (char*)d_ws;
  auto take = [&](size_t bytes) { char* p = w; w += bytes; return p; };
  h16*   Win    = (h16*)take(3145728ull*2);   // Wall: Win|Wpos|Wout contiguous
  h16*   Wpos   = (h16*)take(1048576ull*2);
  h16*   Wout   = (h16*)take(1048576ull*2);
  float* bin    = (float*)take(3072*4);
  float* bpos   = (float*)take(1024*4);
  float* bout   = (float*)take(1024*4);
  float* rw     = (float*)take(1024*4);
  float* rr     = (float*)take(1024*4);
  h16*   in_h   = (h16*)take(2097152ull*2);   // cast_h: in_h|pos_h contiguous
  h16*   pos_h  = (h16*)take(4192256ull*2);   // OOB-read pad: buffers follow
  h16*   qrwb   = (h16*)take(2097152ull*2);
  h16*   qrrb   = (h16*)take(2097152ull*2);
  h16*   kb     = (h16*)take(2097152ull*2);
  h16*   vbt    = (h16*)take(2097152ull*2);
  h16*   rb     = (h16*)take(4194304ull*2);
  float* o_part = (float*)take(4ull*2097152ull*4);
  float* ml     = (float*)take(4ull*65536ull*4);
  h16*   attn_h = (h16*)take(2097152ull*2);

  hypernet_kernel<<<3364, 256, 0, stream>>>(fac, w_in, w_pos, w_out, bin_w, bpos_w, bout_w,
                                            rw_w, rr_w, Win, bin, bpos, bout,
                                            rw, rr, rb, input, pos, in_h);
  gemm_lds_kernel<0><<<dim3(24, 16), 256, 0, stream>>>(in_h, Win, bin, 2048, 3072, 1024,
                                                       nullptr, rw, rr, qrwb, qrrb, kb, vbt);
  gemm_lds_kernel<1><<<dim3(8, 32), 256, 0, stream>>>(pos_h, Wpos, bpos, 4094, 1024, 1024,
                                                      nullptr, nullptr, nullptr, rb, nullptr, nullptr, nullptr);
  flash_kernel<<<dim3(16, 32, 4), 256, 0, stream>>>(qrwb, qrrb, kb, vbt, rb, o_part, ml);
  combine_kernel<<<2048, 256, 0, stream>>>(o_part, ml, attn_h);
  gemm_lds_kernel<2><<<dim3(8, 16), 256, 0, stream>>>(attn_h, Wout, bout, 2048, 1024, 1024,
                                                      out, nullptr, nullptr, nullptr, nullptr, nullptr, nullptr);
}

// Round 5
// 364.194 us; speedup vs baseline: 1.0191x; 1.0191x over previous
//
#include <hip/hip_runtime.h>

// MPRelativeSelfMultiheadAttn on gfx950.
// streaming hypernet (1280 persistent-ish blocks, explicit double-buffered
// 2-row steps => 8 loads in flight) -> fp16 MFMA GEMMs (global_load_lds with
// XOR-swizzled gather => conflict-free ds_read_b128) -> V transpose ->
// j-split(4) flash attention (rel_shift fused, online softmax) -> combine -> out GEMM.

typedef _Float16 h16;
typedef _Float16 h16x8 __attribute__((ext_vector_type(8)));
typedef _Float16 h16x4 __attribute__((ext_vector_type(4)));
typedef float f32x4 __attribute__((ext_vector_type(4)));

static __device__ __forceinline__ f32x4 mfma16(h16x8 a, h16x8 b, f32x4 c) {
  return __builtin_amdgcn_mfma_f32_16x16x32_f16(a, b, c, 0, 0, 0);
}
static __device__ __forceinline__ void gload16(const void* g, void* l) {
  __builtin_amdgcn_global_load_lds((const __attribute__((address_space(1))) void*)g,
                                   (__attribute__((address_space(3))) void*)l, 16, 0, 0);
}

// ---------------- hypernet + casts ----------------
// blocks [0,1280): weight rows, 4096 contiguous rows/block, 16 rows/thread,
//   8 steps x 2 rows, double-buffered loads. Table boundaries on block edges.
// [1280,1316): biases + rb pad (1 row/thread).
// [1316,7458): fp32->fp16 casts (1 float4/thread).
__global__ __launch_bounds__(256, 2) void hypernet_kernel(
    const float* __restrict__ fac,
    const float* __restrict__ w_in, const float* __restrict__ w_pos,
    const float* __restrict__ w_out, const float* __restrict__ b_in_w,
    const float* __restrict__ b_pos_w, const float* __restrict__ b_out_w,
    const float* __restrict__ rw_w, const float* __restrict__ rr_w,
    h16* __restrict__ Wall,                 // Win|Wpos|Wout contiguous
    float* __restrict__ bin, float* __restrict__ bpos, float* __restrict__ bout,
    float* __restrict__ rw, float* __restrict__ rr, h16* __restrict__ rb,
    const float* __restrict__ input, const float* __restrict__ pos,
    h16* __restrict__ cast_h)               // in_h|pos_h contiguous
{
  const int tid = threadIdx.x;
  const float f0=fac[0],f1=fac[1],f2=fac[2],f3=fac[3],
              f4=fac[4],f5=fac[5],f6=fac[6],f7=fac[7];
#define DOT(a,b) ((a).x*f0+(a).y*f1+(a).z*f2+(a).w*f3+(b).x*f4+(b).y*f5+(b).z*f6+(b).w*f7)

  if (blockIdx.x < 1280) {
    const int b = blockIdx.x;
    const float* tbl; size_t rowbase;
    if (b < 768)       { tbl = w_in;  rowbase = (size_t)b*4096; }
    else if (b < 1024) { tbl = w_pos; rowbase = (size_t)b*4096 - 3145728; }
    else               { tbl = w_out; rowbase = (size_t)b*4096 - 4194304; }
    const size_t outbase = (size_t)b*4096;
    float4 cur[4], nxt[4];
    {
      const float4* p0 = reinterpret_cast<const float4*>(tbl + (rowbase + tid)*8);
      const float4* p1 = reinterpret_cast<const float4*>(tbl + (rowbase + 256 + tid)*8);
      cur[0]=p0[0]; cur[1]=p0[1]; cur[2]=p1[0]; cur[3]=p1[1];
    }
#pragma unroll
    for (int s = 0; s < 8; ++s) {
      if (s < 7) {
        const float4* p0 = reinterpret_cast<const float4*>(tbl + (rowbase + (s+1)*512 + tid)*8);
        const float4* p1 = reinterpret_cast<const float4*>(tbl + (rowbase + (s+1)*512 + 256 + tid)*8);
        nxt[0]=p0[0]; nxt[1]=p0[1]; nxt[2]=p1[0]; nxt[3]=p1[1];
      }
      Wall[outbase + s*512 + tid]       = (h16)DOT(cur[0], cur[1]);
      Wall[outbase + s*512 + 256 + tid] = (h16)DOT(cur[2], cur[3]);
#pragma unroll
      for (int q = 0; q < 4; ++q) cur[q] = nxt[q];
    }
    return;
  }
  if (blockIdx.x < 1316) {                  // biases + rb pad
    int idx = (blockIdx.x - 1280) * 256 + tid;
    if (idx < 3072) {
      const float4* s = reinterpret_cast<const float4*>(b_in_w + (size_t)idx*8);
      bin[idx] = DOT(s[0], s[1]); return;
    }
    idx -= 3072;
    if (idx < 1024) {
      const float4* s = reinterpret_cast<const float4*>(b_pos_w + (size_t)idx*8);
      bpos[idx] = DOT(s[0], s[1]); return;
    }
    idx -= 1024;
    if (idx < 1024) {
      const float4* s = reinterpret_cast<const float4*>(b_out_w + (size_t)idx*8);
      bout[idx] = DOT(s[0], s[1]); return;
    }
    idx -= 1024;
    if (idx < 1024) {
      const float4* s = reinterpret_cast<const float4*>(rw_w + (size_t)idx*8);
      rw[idx] = DOT(s[0], s[1]); return;
    }
    idx -= 1024;
    if (idx < 1024) {
      const float4* s = reinterpret_cast<const float4*>(rr_w + (size_t)idx*8);
      rr[idx] = DOT(s[0], s[1]); return;
    }
    idx -= 1024;
    if (idx < 2048)
      rb[(((size_t)(idx >> 6)) << 17) + 2047*64 + (idx & 63)] = (h16)0.f;
    return;
  }
  { // casts: float4 index space [0, 1572352) = input(524288) | pos(1048064)
    const int g = (blockIdx.x - 1316) * 256 + tid;
    float4 v = (g < 524288) ? reinterpret_cast<const float4*>(input)[g]
                            : reinterpret_cast<const float4*>(pos)[g - 524288];
    h16x4 o = { (h16)v.x, (h16)v.y, (h16)v.z, (h16)v.w };
    reinterpret_cast<h16x4*>(cast_h)[g] = o;
  }
#undef DOT
}

// ---------------- GEMM C = A[MxK] * Bw[NxK]^T, swizzled global_load_lds ----------------
// MODE 0: qkv -> qrw,qrr,kb,vb per-head; MODE 1: r -> rb; MODE 2: fp32 C + bias
template <int MODE>
__global__ __launch_bounds__(256) void gemm_lds_kernel(
    const h16* __restrict__ A, const h16* __restrict__ Bw,
    const float* __restrict__ bias, int M, int N, int K,
    float* __restrict__ Cout,
    const float* __restrict__ rwv, const float* __restrict__ rrv,
    h16* __restrict__ o0, h16* __restrict__ o1,
    h16* __restrict__ o2, h16* __restrict__ o3)
{
  __shared__ __align__(16) h16 a_sm[128*64];
  __shared__ __align__(16) h16 b_sm[128*64];
  const int tid = threadIdx.x, lane = tid & 63, wave = tid >> 6;
  const int quad = lane >> 4, t16 = lane & 15;
  const int wm = wave >> 1, wn = wave & 1;
  const int m0 = blockIdx.y * 128, n0 = blockIdx.x * 128;
  const int lrow = lane >> 3, lgran = lane & 7;
  const int gsw = (lgran ^ lrow) * 8;          // swizzled source col offset (h16)
  const int xg0 = (quad ^ (t16 & 7)) * 8;      // fragment granule, kc=0
  const int xg1 = xg0 ^ 32;                    // kc=1

  f32x4 acc[4][4];
#pragma unroll
  for (int i = 0; i < 4; ++i)
#pragma unroll
    for (int j = 0; j < 4; ++j) acc[i][j] = (f32x4){0.f,0.f,0.f,0.f};

  for (int k0 = 0; k0 < K; k0 += 64) {
    __syncthreads();
#pragma unroll
    for (int s = 0; s < 4; ++s) {
      int rbase = wave*32 + s*8;
      gload16(A  + (size_t)(m0 + rbase + lrow)*K + k0 + gsw, a_sm + rbase*64);
      gload16(Bw + (size_t)(n0 + rbase + lrow)*K + k0 + gsw, b_sm + rbase*64);
    }
    __syncthreads();
#pragma unroll
    for (int kc = 0; kc < 2; ++kc) {
      const int xg = kc ? xg1 : xg0;
      h16x8 af[4], bfr[4];
#pragma unroll
      for (int i = 0; i < 4; ++i) {
        af[i]  = *reinterpret_cast<const h16x8*>(a_sm + (wm*64 + i*16 + t16)*64 + xg);
        bfr[i] = *reinterpret_cast<const h16x8*>(b_sm + (wn*64 + i*16 + t16)*64 + xg);
      }
#pragma unroll
      for (int i = 0; i < 4; ++i)
#pragma unroll
        for (int j = 0; j < 4; ++j)
          acc[i][j] = mfma16(af[i], bfr[j], acc[i][j]);
    }
  }

  // epilogue: C/D layout row=(lane>>4)*4+reg, col=lane&15
#pragma unroll
  for (int i = 0; i < 4; ++i) {
    int mb = m0 + wm*64 + i*16 + quad*4;
#pragma unroll
    for (int j = 0; j < 4; ++j) {
      int n = n0 + wn*64 + j*16 + t16;
      float bv = bias[n];
      if (MODE == 2) {
#pragma unroll
        for (int r = 0; r < 4; ++r)
          Cout[(size_t)(mb + r)*N + n] = acc[i][j][r] + bv;
      } else if (MODE == 0) {
        int nn = n & 1023, sec = n >> 10, hh = nn >> 6, d = nn & 63;
        float rwb = rwv[nn], rrb = rrv[nn];
#pragma unroll
        for (int r = 0; r < 4; ++r) {
          int m = mb + r, t = m >> 1, b = m & 1;
          size_t off = ((size_t)((b << 4) + hh) << 16) + (t << 6) + d;
          float v = acc[i][j][r] + bv;
          if (sec == 0)      { o0[off] = (h16)(v + rwb); o1[off] = (h16)(v + rrb); }
          else if (sec == 1) { o2[off] = (h16)v; }
          else               { o3[off] = (h16)v; }
        }
      } else { // MODE 1
        int hh = n >> 6, d = n & 63;
#pragma unroll
        for (int r = 0; r < 4; ++r) {
          int m = mb + r;
          if (m < M) {
            int rel = m >> 1, b = m & 1;
            o0[(((size_t)((b << 4) + hh)) << 17) + (rel << 6) + d] = (h16)(acc[i][j][r] + bv);
          }
        }
      }
    }
  }
}

// ---------------- V transpose: vb [BH][T][64] -> vbt [BH][64][T] ----------------
__global__ __launch_bounds__(256) void transpose_v_kernel(
    const h16* __restrict__ vb, h16* __restrict__ vbt)
{
  __shared__ h16 tile[64*72];
  const int bh = blockIdx.y, t0 = blockIdx.x * 64;
  const int r = threadIdx.x >> 3, c = (threadIdx.x & 7) * 8;
  const h16* src = vb + ((size_t)bh << 16) + (size_t)(t0 + r)*64 + c;
  *reinterpret_cast<h16x8*>(tile + r*72 + c)        = *reinterpret_cast<const h16x8*>(src);
  *reinterpret_cast<h16x8*>(tile + (r + 32)*72 + c) = *reinterpret_cast<const h16x8*>(src + 32*64);
  __syncthreads();
  h16x8 o0, o1;
#pragma unroll
  for (int e = 0; e < 8; ++e) {
    o0[e] = tile[(c + e)*72 + r];
    o1[e] = tile[(c + e)*72 + r + 32];
  }
  h16* dst = vbt + ((size_t)bh << 16) + (size_t)r*1024 + t0 + c;
  *reinterpret_cast<h16x8*>(dst)            = o0;
  *reinterpret_cast<h16x8*>(dst + 32*1024)  = o1;
}

// ---------------- flash attention, j-split(4), swizzled staging ----------------
__global__ __launch_bounds__(256) void flash_kernel(
    const h16* __restrict__ qrw, const h16* __restrict__ qrr,
    const h16* __restrict__ kb, const h16* __restrict__ vbt,
    const h16* __restrict__ rb,
    float* __restrict__ o_part, float* __restrict__ ml_part)
{
  __shared__ __align__(16) h16 k_sm[64*64];
  __shared__ __align__(16) h16 vt_sm[64*64];
  __shared__ __align__(16) h16 r_sm[128*64];   // reused as BD/P spill after barrier

  const int tid = threadIdx.x, lane = tid & 63, wave = tid >> 6;
  const int quad = lane >> 4, t16 = lane & 15;
  const int bh = blockIdx.y, i0 = blockIdx.x * 64, jh = blockIdx.z;
  const size_t base  = (size_t)bh << 16;
  const size_t rbase = (size_t)bh << 17;
  const int iw = i0 + wave * 16;
  const int lrow = lane >> 3, lgran = lane & 7;
  const int gsw = (lgran ^ lrow) * 8;
  const int xg0 = (quad ^ (t16 & 7)) * 8;
  const int xg1 = xg0 ^ 32;

  h16x8 a_rw[2], a_rr[2];
  {
    const h16* p = qrw + base + (size_t)(iw + t16)*64 + quad*8;
    a_rw[0] = *reinterpret_cast<const h16x8*>(p);
    a_rw[1] = *reinterpret_cast<const h16x8*>(p + 32);
    const h16* p2 = qrr + base + (size_t)(iw + t16)*64 + quad*8;
    a_rr[0] = *reinterpret_cast<const h16x8*>(p2);
    a_rr[1] = *reinterpret_cast<const h16x8*>(p2 + 32);
  }

  f32x4 o_acc[4];
#pragma unroll
  for (int dc = 0; dc < 4; ++dc) o_acc[dc] = (f32x4){0.f,0.f,0.f,0.f};
  float m_run[4] = {-1e30f,-1e30f,-1e30f,-1e30f};
  float l_run[4] = {0.f,0.f,0.f,0.f};   // per-lane partial; reduced at end

  h16* bdw = r_sm + wave * (16*84);
  const int cb0 = 3 - wave;

  for (int j0 = jh*256; j0 < jh*256 + 256; j0 += 64) {
    __syncthreads();
    { // swizzled staging
#pragma unroll
      for (int s = 0; s < 2; ++s) {
        int row = wave*16 + s*8;
        gload16(kb  + base + (size_t)(j0 + row + lrow)*64 + gsw, k_sm  + row*64);
        gload16(vbt + base + (size_t)(row + lrow)*1024 + j0 + gsw, vt_sm + row*64);
      }
      const int rel0 = j0 - i0 + 960;
#pragma unroll
      for (int s = 0; s < 4; ++s) {
        int row = wave*32 + s*8;
        gload16(rb + rbase + (size_t)(rel0 + row + lrow)*64 + gsw, r_sm + row*64);
      }
    }
    __syncthreads();

    f32x4 s_ac[4];
#pragma unroll
    for (int c = 0; c < 4; ++c) {
      s_ac[c] = (f32x4){0.f,0.f,0.f,0.f};
      s_ac[c] = mfma16(a_rw[0], *reinterpret_cast<const h16x8*>(k_sm + (c*16 + t16)*64 + xg0), s_ac[c]);
      s_ac[c] = mfma16(a_rw[1], *reinterpret_cast<const h16x8*>(k_sm + (c*16 + t16)*64 + xg1), s_ac[c]);
    }
    f32x4 s_bd[5];
#pragma unroll
    for (int u = 0; u < 5; ++u) {
      s_bd[u] = (f32x4){0.f,0.f,0.f,0.f};
      s_bd[u] = mfma16(a_rr[0], *reinterpret_cast<const h16x8*>(r_sm + ((cb0+u)*16 + t16)*64 + xg0), s_bd[u]);
      s_bd[u] = mfma16(a_rr[1], *reinterpret_cast<const h16x8*>(r_sm + ((cb0+u)*16 + t16)*64 + xg1), s_bd[u]);
    }
    __syncthreads();  // r_sm reads done before spilling into it

    // BD spill (C-layout), stride 84
#pragma unroll
    for (int u = 0; u < 5; ++u)
#pragma unroll
      for (int r = 0; r < 4; ++r)
        bdw[(quad*4 + r)*84 + u*16 + t16] = (h16)s_bd[u][r];

    // combine with relative shift
    float sv[4][4];
#pragma unroll
    for (int c = 0; c < 4; ++c)
#pragma unroll
      for (int r = 0; r < 4; ++r) {
        int il = quad*4 + r;
        float bdv = (float)bdw[il*84 + c*16 + t16 + 15 - il];
        sv[c][r] = (s_ac[c][r] + bdv) * 0.125f;
      }

    // online softmax: shared row max (shfl), per-lane l partial
    float alpha[4];
#pragma unroll
    for (int r = 0; r < 4; ++r) {
      float v = fmaxf(fmaxf(sv[0][r], sv[1][r]), fmaxf(sv[2][r], sv[3][r]));
#pragma unroll
      for (int off = 1; off < 16; off <<= 1) v = fmaxf(v, __shfl_xor(v, off, 64));
      float mn = fmaxf(m_run[r], v);
      alpha[r] = __expf(m_run[r] - mn);
      m_run[r] = mn;
    }
#pragma unroll
    for (int r = 0; r < 4; ++r) {
      float s0 = 0.f;
#pragma unroll
      for (int c = 0; c < 4; ++c) {
        float p = __expf(sv[c][r] - m_run[r]);
        sv[c][r] = p; s0 += p;
      }
      l_run[r] = l_run[r]*alpha[r] + s0;   // per-lane; reduce at end
    }
#pragma unroll
    for (int dc = 0; dc < 4; ++dc) {
      f32x4 t = o_acc[dc];
#pragma unroll
      for (int r = 0; r < 4; ++r) t[r] *= alpha[r];
      o_acc[dc] = t;
    }
    // P round-trip (stride 72, 2-way free)
    h16* pw = bdw;
#pragma unroll
    for (int c = 0; c < 4; ++c)
#pragma unroll
      for (int r = 0; r < 4; ++r)
        pw[(quad*4 + r)*72 + c*16 + t16] = (h16)sv[c][r];

    h16x8 ap0 = *reinterpret_cast<const h16x8*>(pw + t16*72 + quad*8);
    h16x8 ap1 = *reinterpret_cast<const h16x8*>(pw + t16*72 + 32 + quad*8);
#pragma unroll
    for (int dc = 0; dc < 4; ++dc) {
      h16x8 bv0 = *reinterpret_cast<const h16x8*>(vt_sm + (dc*16 + t16)*64 + xg0);
      h16x8 bv1 = *reinterpret_cast<const h16x8*>(vt_sm + (dc*16 + t16)*64 + xg1);
      o_acc[dc] = mfma16(ap0, bv0, o_acc[dc]);
      o_acc[dc] = mfma16(ap1, bv1, o_acc[dc]);
    }
  }

  // reduce l across the quad's 16 lanes, then write partials
#pragma unroll
  for (int r = 0; r < 4; ++r) {
    float l = l_run[r];
#pragma unroll
    for (int off = 1; off < 16; off <<= 1) l += __shfl_xor(l, off, 64);
    l_run[r] = l;
  }
  const size_t obase = ((size_t)jh*32 + bh) * 1024 * 64;
#pragma unroll
  for (int r = 0; r < 4; ++r) {
    int i = iw + quad*4 + r;
#pragma unroll
    for (int dc = 0; dc < 4; ++dc)
      o_part[obase + (size_t)i*64 + dc*16 + t16] = o_acc[dc][r];
    if (t16 == 0) {
      size_t mo = (((size_t)jh*32 + bh)*1024 + i)*2;
      ml_part[mo]     = m_run[r];
      ml_part[mo + 1] = l_run[r];
    }
  }
}

// ---------------- combine 4 j-parts -> attn_h [(t*2+b)][E] h16 ----------------
__global__ __launch_bounds__(256) void combine_kernel(
    const float* __restrict__ o_part, const float* __restrict__ ml_part,
    h16* __restrict__ attn_h)
{
  int gid = blockIdx.x * 256 + threadIdx.x;   // 524288
  int row = gid >> 4;                          // bh*1024 + i
  int d4 = (gid & 15) * 4;
  float m[4], l[4];
#pragma unroll
  for (int p = 0; p < 4; ++p) {
    m[p] = ml_part[p*65536 + row*2];
    l[p] = ml_part[p*65536 + row*2 + 1];
  }
  float M = fmaxf(fmaxf(m[0], m[1]), fmaxf(m[2], m[3]));
  float e[4], den = 0.f;
#pragma unroll
  for (int p = 0; p < 4; ++p) { e[p] = __expf(m[p] - M); den += e[p]*l[p]; }
  float inv = 1.f / den;
  float4 acc = {0.f,0.f,0.f,0.f};
#pragma unroll
  for (int p = 0; p < 4; ++p) {
    float4 O = *reinterpret_cast<const float4*>(o_part + (size_t)p*2097152 + (size_t)row*64 + d4);
    acc.x += e[p]*O.x; acc.y += e[p]*O.y; acc.z += e[p]*O.z; acc.w += e[p]*O.w;
  }
  int bh = row >> 10, i = row & 1023, b = bh >> 4, h = bh & 15;
  h16x4 o = { (h16)(acc.x*inv), (h16)(acc.y*inv), (h16)(acc.z*inv), (h16)(acc.w*inv) };
  *reinterpret_cast<h16x4*>(attn_h + ((size_t)(i*2 + b))*1024 + h*64 + d4) = o;
}

extern "C" void kernel_launch(void* const* d_in, const int* in_sizes, int n_in,
                              void* d_out, int out_size, void* d_ws, size_t ws_size,
                              hipStream_t stream)
{
  const float* input  = (const float*)d_in[0];
  const float* pos    = (const float*)d_in[1];
  const float* fac    = (const float*)d_in[2];
  const float* w_in   = (const float*)d_in[3];
  const float* w_pos  = (const float*)d_in[4];
  const float* w_out  = (const float*)d_in[5];
  const float* bin_w  = (const float*)d_in[6];
  const float* bpos_w = (const float*)d_in[7];
  const float* bout_w = (const float*)d_in[8];
  const float* rw_w   = (const float*)d_in[9];
  const float* rr_w   = (const float*)d_in[10];
  float* out = (float*)d_out;
  (void)in_sizes; (void)n_in; (void)out_size; (void)ws_size;

  char* w = (char*)d_ws;
  auto take = [&](size_t bytes) { char* p = w; w += bytes; return p; };
  h16*   Win    = (h16*)take(3145728ull*2);   // Wall: Win|Wpos|Wout contiguous
  h16*   Wpos   = (h16*)take(1048576ull*2);
  h16*   Wout   = (h16*)take(1048576ull*2);
  float* bin    = (float*)take(3072*4);
  float* bpos   = (float*)take(1024*4);
  float* bout   = (float*)take(1024*4);
  float* rw     = (float*)take(1024*4);
  float* rr     = (float*)take(1024*4);
  h16*   in_h   = (h16*)take(2097152ull*2);   // cast_h: in_h|pos_h contiguous
  h16*   pos_h  = (h16*)take(4192256ull*2);   // OOB-read pad: buffers follow
  h16*   qrwb   = (h16*)take(2097152ull*2);
  h16*   qrrb   = (h16*)take(2097152ull*2);
  h16*   kb     = (h16*)take(2097152ull*2);
  h16*   vb     = (h16*)take(2097152ull*2);
  h16*   vbt    = (h16*)take(2097152ull*2);
  h16*   rb     = (h16*)take(4194304ull*2);
  float* o_part = (float*)take(4ull*2097152ull*4);
  float* ml     = (float*)take(4ull*65536ull*4);
  h16*   attn_h = (h16*)take(2097152ull*2);

  hypernet_kernel<<<7458, 256, 0, stream>>>(fac, w_in, w_pos, w_out, bin_w, bpos_w, bout_w,
                                            rw_w, rr_w, Win, bin, bpos, bout,
                                            rw, rr, rb, input, pos, in_h);
  gemm_lds_kernel<0><<<dim3(24, 16), 256, 0, stream>>>(in_h, Win, bin, 2048, 3072, 1024,
                                                       nullptr, rw, rr, qrwb, qrrb, kb, vb);
  gemm_lds_kernel<1><<<dim3(8, 32), 256, 0, stream>>>(pos_h, Wpos, bpos, 4094, 1024, 1024,
                                                      nullptr, nullptr, nullptr, rb, nullptr, nullptr, nullptr);
  transpose_v_kernel<<<dim3(16, 32), 256, 0, stream>>>(vb, vbt);
  flash_kernel<<<dim3(16, 32, 4), 256, 0, stream>>>(qrwb, qrrb, kb, vbt, rb, o_part, ml);
  combine_kernel<<<2048, 256, 0, stream>>>(o_part, ml, attn_h);
  gemm_lds_kernel<2><<<dim3(8, 16), 256, 0, stream>>>(attn_h, Wout, bout, 2048, 1024, 1024,
                                                      out, nullptr, nullptr, nullptr, nullptr, nullptr, nullptr);
}